// Round 6
// baseline (279.066 us; speedup 1.0000x reference)
//
#include <hip/hip_runtime.h>
#include <stdint.h>

#define T_LEN 524288
#define NBLK 1024          // grid; must be co-resident (see launch_bounds math)
#define EPB (T_LEN / NBLK) // 512 x-elements per block in phase A
#define SEGL 40            // spikes per chunk; 4 chunks/block (4 waves)
#define WARMUP 32
#define HROW (SEGL + 1)    // 41, odd stride -> conflict-free

typedef float v4f __attribute__((ext_vector_type(4)));

// ---- workspace layout (bytes); [0, 8192) is memset to 0 each launch ----
static const size_t OFF_STATE = 0;      // NBLK ints: scan state (tag<<30 | count)
static const size_t OFF_DONE  = 4096;   // 1 int: barrier counter
static const size_t OFF_NSPK  = 4100;   // 1 int: N
static const size_t OFF_SPK   = 8192;   // T ints: spike times

struct __align__(16) WaveLds {
    float  hh[32 * HROW + 32];      // h history + sink row (5376 B)
    float2 sx[SEGL + WARMUP + 8];   // staged (t, x_t)       (640 B)
    float  hbc[96];                 // h broadcast / a,b     (384 B)
};                                  // 6400 B

__global__ __launch_bounds__(256, 4)   // 4 waves/EU min -> <=128 VGPR, >=4 blk/CU
void k_fused(const float* __restrict__ x,
             const float* __restrict__ Wih,
             const float* __restrict__ Whh,
             const float* __restrict__ bih,
             const float* __restrict__ bhh,
             const float* __restrict__ Wv,
             const float* __restrict__ bv,
             const float* __restrict__ Wsc,
             const float* __restrict__ bs,
             int* __restrict__ state,
             int* __restrict__ done,
             int* __restrict__ nspk,
             int* __restrict__ spk,
             float* __restrict__ out)
{
    __shared__ __align__(16) unsigned char smem[4 * sizeof(WaveLds)];
    __shared__ int sh_wtot[4];
    __shared__ int sh_g0;
    __shared__ int sh_N;

    const int tid = threadIdx.x;
    const int lane = tid & 63;
    const int wv = tid >> 6;
    const int bid = blockIdx.x;

    // ================= Phase A: mask + global scan + scatter =================
    {
        float* tile = (float*)smem;            // [EPB + 130] floats
        const int bs_ = bid * EPB;
        for (int j = tid; j < EPB + 130; j += 256) {
            int g = bs_ - 130 + j;
            tile[j] = (g >= 0) ? x[g] : 0.f;
        }
        __syncthreads();

        const int loc = tid * 2;
        float s = 0.f;
        #pragma unroll 16
        for (int m = 0; m < 128; ++m) {
            float v = tile[loc + 2 + m];
            s = fmaf(v, v, s);
        }
        int mbit[2]; int tvals[2];
        int tsum = 0;
        #pragma unroll
        for (int it = 0; it < 2; ++it) {
            int t = bs_ + loc + it;
            int c = t < 128 ? (t < 1 ? 1 : t) : 128;
            float rms = sqrtf(fmaxf(s, 0.f) / (float)c) + 1e-8f;
            float xt = tile[loc + 130 + it];
            float pr = 2.f * tile[loc + 129 + it] - tile[loc + 128 + it];
            bool m = (t < 2) || (fabsf(xt - pr) > 2.5f * rms);
            mbit[it] = m ? 1 : 0; tvals[it] = t;
            tsum += mbit[it];
            float a = tile[loc + 130 + it], d = tile[loc + 2 + it];
            s = fmaf(a, a, s) - d * d;
            out[T_LEN + 1 + t] = m ? 1.f : 0.f;
        }

        // block scan of tsum
        int incl = tsum;
        for (int d = 1; d < 64; d <<= 1) {
            int u = __shfl_up(incl, d, 64);
            if (lane >= d) incl += u;
        }
        if (lane == 63) sh_wtot[wv] = incl;
        __syncthreads();
        int woff = 0;
        for (int i2 = 0; i2 < wv; i2++) woff += sh_wtot[i2];
        int texcl = woff + incl - tsum;
        int btot = sh_wtot[0] + sh_wtot[1] + sh_wtot[2] + sh_wtot[3];

        // publish aggregate, wave-parallel lookback (wave 0)
        if (tid == 0) atomicExch(&state[bid], (int)((1u << 30) | (unsigned)btot));
        if (tid < 64) {
            int excl = 0;
            int look = bid - 1;
            while (look >= 0) {
                int idx = look - lane;
                unsigned st = (idx >= 0) ? (unsigned)atomicAdd(&state[idx], 0)
                                         : (2u << 30);
                unsigned tag = st >> 30;
                unsigned long long pm = __ballot(tag == 2u);
                unsigned long long im = __ballot(tag == 0u);
                int fp = pm ? (__ffsll((long long)pm) - 1) : 64;
                unsigned long long below = (fp >= 64) ? ~0ull : ((1ull << fp) - 1ull);
                if (im & below) { __builtin_amdgcn_s_sleep(1); continue; }
                int contrib = (lane <= fp) ? (int)(st & 0x3FFFFFFFu) : 0;
                for (int d = 32; d; d >>= 1) contrib += __shfl_down(contrib, d, 64);
                excl += __shfl(contrib, 0, 64);
                if (fp < 64) break;
                look -= 64;
            }
            if (lane == 0) {
                int inclv = excl + btot;
                atomicExch(&state[bid], (int)((2u << 30) | (unsigned)inclv));
                sh_g0 = excl;
                if (bid == NBLK - 1) {
                    *nspk = inclv;
                    out[T_LEN] = (float)inclv;
                }
            }
        }
        __syncthreads();
        int g0 = sh_g0 + texcl;
        if (mbit[0]) spk[g0] = tvals[0];
        if (mbit[1]) spk[g0 + mbit[0]] = tvals[1];
    }

    // ================= device-wide barrier =================
    if (tid == 0) {
        __threadfence();
        atomicAdd(done, 1);
        while (atomicAdd(done, 0) < NBLK) __builtin_amdgcn_s_sleep(2);
        sh_N = atomicAdd(nspk, 0);
    }
    __syncthreads();
    __threadfence();
    const int N = sh_N;

    // ================= Phase B: GRU chain (1 wave = 1 chunk) =================
    const int i = lane & 31;
    const int p = lane >> 5;
    WaveLds& L = ((WaveLds*)smem)[wv];

    // per-lane half-row weights as float4 (v_pk_fma_f32)
    v4f Wr4[4], Wz4[4], Wn4[4];
    #pragma unroll
    for (int q = 0; q < 4; q++) {
        Wr4[q] = *(const v4f*)&Whh[i * 32        + 16 * p + 4 * q];
        Wz4[q] = *(const v4f*)&Whh[(32 + i) * 32 + 16 * p + 4 * q];
        Wn4[q] = *(const v4f*)&Whh[(64 + i) * 32 + 16 * p + 4 * q];
    }
    const float z0 = p ? 0.f : 1.f;       // input terms only on half 0
    const float wr0 = z0 * Wih[i * 2],        wr1 = z0 * Wih[i * 2 + 1];
    const float wz0 = z0 * Wih[(32 + i) * 2], wz1 = z0 * Wih[(32 + i) * 2 + 1];
    const float br  = z0 * (bih[i] + bhh[i]);
    const float bz  = z0 * (bih[32 + i] + bhh[32 + i]);
    const float bnh = z0 * bhh[64 + i];
    const float wn0 = z0 * Wih[(64 + i) * 2], wn1 = z0 * Wih[(64 + i) * 2 + 1];
    const float bni = z0 * bih[64 + i];

    const int xidx = (lane ^ 32) * 4;     // xor-32 combine index

    for (int c = bid * 4 + wv; c * SEGL < N; c += NBLK * 4) {
        const int start = c * SEGL;
        const int end = min(start + SEGL, N);
        const int s0 = max(start - WARMUP, 0);
        const int cnt = end - s0;
        const int jw = start - s0;

        for (int j = lane; j < cnt + 3; j += 64) {
            int idx = min(max(s0 - 1 + j, 0), N - 1);
            int t = spk[idx];
            L.sx[j] = make_float2((float)t, x[t]);
        }
        __builtin_amdgcn_wave_barrier();

        v4f hs4[4];
        #pragma unroll
        for (int q = 0; q < 4; q++) hs4[q] = (v4f)0.f;
        float hold = 0.f;

        float2 p0 = L.sx[0], p1 = L.sx[1];
        for (int j = 0; j < cnt; ++j) {
            float2 p2 = L.sx[j + 2];
            float d  = (p1.x - p0.x) * 0.0078125f;
            float xt = p1.y;

            float ar_in = fmaf(wr1, d, fmaf(wr0, xt, br));
            float az_in = fmaf(wz1, d, fmaf(wz0, xt, bz));
            float gin   = fmaf(wn1, d, fmaf(wn0, xt, bni));
            v4f sr = (v4f)0.f, sz = (v4f)0.f, sn = (v4f)0.f;
            #pragma unroll
            for (int q = 0; q < 4; q++) {     // 24 v_pk_fma_f32
                sr = Wr4[q] * hs4[q] + sr;
                sz = Wz4[q] * hs4[q] + sz;
                sn = Wn4[q] * hs4[q] + sn;
            }
            float ar = ar_in + ((sr.x + sr.z) + (sr.y + sr.w));
            float az = az_in + ((sz.x + sz.z) + (sz.y + sz.w));
            float an = bnh   + ((sn.x + sn.z) + (sn.y + sn.w));
            float gn = gin;
            ar += __int_as_float(__builtin_amdgcn_ds_bpermute(xidx, __float_as_int(ar)));
            az += __int_as_float(__builtin_amdgcn_ds_bpermute(xidx, __float_as_int(az)));
            float anx = an + __int_as_float(__builtin_amdgcn_ds_bpermute(xidx, __float_as_int(an)));
            float gnx = gn + __int_as_float(__builtin_amdgcn_ds_bpermute(xidx, __float_as_int(gn)));

            float r = __builtin_amdgcn_rcpf(1.f + __builtin_amdgcn_exp2f(-1.44269504089f * ar));
            float z = __builtin_amdgcn_rcpf(1.f + __builtin_amdgcn_exp2f(-1.44269504089f * az));
            float npre = fmaf(r, anx, gnx);
            float en = __builtin_amdgcn_exp2f(2.88539008178f * npre);
            float n = fmaf(-2.f, __builtin_amdgcn_rcpf(1.f + en), 1.f);
            float hnew = fmaf(z, hold - n, n);
            hold = hnew;

            // h history (lanes<32, post-warmup); others hit sink row
            bool okst = (p == 0) & (j >= jw);
            int addr = okst ? (i * HROW + (j - jw)) : (32 * HROW + i);
            L.hh[addr] = hnew;

            // broadcast: write h_i, read own 16-half as 4 x b128
            L.hbc[i] = hnew;
            const v4f* hb4 = (const v4f*)&L.hbc[16 * p];
            hs4[0] = hb4[0]; hs4[1] = hb4[1]; hs4[2] = hb4[2]; hs4[3] = hb4[3];
            p0 = p1; p1 = p2;
        }
        __builtin_amdgcn_wave_barrier();

        // epilogue 1: a,b for ALL spikes of the chunk (lanes 0..SEGL-1)
        const float bvv = *bv, bss = *bs;
        if (lane < SEGL && start + lane < end) {
            float a = bvv, b = bss;
            #pragma unroll
            for (int k = 0; k < 32; k++) {
                float hv = L.hh[k * HROW + lane];
                a = fmaf(hv, Wv[k], a);
                b = fmaf(hv, Wsc[k], b);
            }
            L.hbc[lane] = a;
            L.hbc[48 + lane] = b;
        }
        __builtin_amdgcn_wave_barrier();

        // epilogue 2: expand out[t] for t in [spk[start], next chunk's first)
        const int tlo = (int)L.sx[jw + 1].x;
        const int thi = (end == N) ? T_LEN : (int)L.sx[cnt + 1].x;
        for (int t = tlo + lane; t < thi; t += 64) {
            float tf = (float)t;
            int lo = jw + 1, hi = cnt;
            #pragma unroll
            for (int itb = 0; itb < 6; ++itb) {
                int mid = (lo + hi + 1) >> 1;
                bool le = L.sx[mid].x <= tf;
                lo = le ? mid : lo;
                hi = le ? hi : mid - 1;
            }
            int sp = lo - (jw + 1);
            float a = L.hbc[sp], b = L.hbc[48 + sp];
            float tp = L.sx[lo].x;
            out[t] = fmaf(b, (tf - tp) * 0.0078125f, a);
        }
        __builtin_amdgcn_wave_barrier();
    }
}

extern "C" void kernel_launch(void* const* d_in, const int* in_sizes, int n_in,
                              void* d_out, int out_size, void* d_ws, size_t ws_size,
                              hipStream_t stream)
{
    const float* x   = (const float*)d_in[0];
    const float* Wih = (const float*)d_in[1];
    const float* Whh = (const float*)d_in[2];
    const float* bih = (const float*)d_in[3];
    const float* bhh = (const float*)d_in[4];
    const float* Wv  = (const float*)d_in[5];
    const float* bv  = (const float*)d_in[6];
    const float* Wsc = (const float*)d_in[7];
    const float* bs  = (const float*)d_in[8];
    float* out = (float*)d_out;

    char* ws = (char*)d_ws;
    int* state = (int*)(ws + OFF_STATE);
    int* done  = (int*)(ws + OFF_DONE);
    int* nspk  = (int*)(ws + OFF_NSPK);
    int* spk   = (int*)(ws + OFF_SPK);

    hipMemsetAsync(ws, 0, 8192, stream);   // zero scan states + barrier + N
    k_fused<<<NBLK, 256, 0, stream>>>(x, Wih, Whh, bih, bhh, Wv, bv, Wsc, bs,
                                      state, done, nspk, spk, out);
}

// Round 7
// 159.514 us; speedup vs baseline: 1.7495x; 1.7495x over previous
//
#include <hip/hip_runtime.h>
#include <stdint.h>

#define T_LEN 524288
#define PREP_BLKS 512
#define CHAIN_BLKS 2048
#define SEGL 80
#define WARMUP 32
#define HROW (SEGL + 1)     // 81, odd stride -> conflict-free

typedef float v4f __attribute__((ext_vector_type(4)));

// ---- workspace layout (bytes); [0, 8192) memset to 0 each launch ----
static const size_t OFF_STATE = 0;      // 512 ints: scan state (tag<<30 | count)
static const size_t OFF_NSPK  = 4096;   // 1 int: N
static const size_t OFF_SPK   = 8192;   // T ints: spike times

// ---- K1: mask + decoupled-lookback global scan + scatter (one kernel) ----
__global__ __launch_bounds__(256) void k_prep(const float* __restrict__ x,
                                              float* __restrict__ out,
                                              int* __restrict__ state,
                                              int* __restrict__ nspk,
                                              int* __restrict__ spk)
{
    __shared__ float tile[1154];          // x[bs-130 .. bs+1024)
    __shared__ int sh_wtot[4];
    __shared__ int sh_g0;
    const int bid = blockIdx.x;
    const int bs = bid * 1024;
    const int tid = threadIdx.x;
    const int lane = tid & 63, wv = tid >> 6;

    for (int j = tid; j < 1154; j += 256) {
        int g = bs - 130 + j;
        tile[j] = (g >= 0) ? x[g] : 0.f;
    }
    __syncthreads();

    const int loc = tid * 4;
    float s = 0.f;
    #pragma unroll 16
    for (int m = 0; m < 128; ++m) { float v = tile[loc + 2 + m]; s = fmaf(v, v, s); }

    int mb[4]; float4 mf; int tsum = 0;
    float* fp_ = &mf.x;
    #pragma unroll
    for (int it = 0; it < 4; ++it) {
        int t = bs + loc + it;
        int c = t < 128 ? (t < 1 ? 1 : t) : 128;
        float rms = sqrtf(fmaxf(s, 0.f) / (float)c) + 1e-8f;
        float xt = tile[loc + 130 + it];
        float pr = 2.f * tile[loc + 129 + it] - tile[loc + 128 + it];
        bool m = (t < 2) || (fabsf(xt - pr) > 2.5f * rms);
        mb[it] = m ? 1 : 0; fp_[it] = m ? 1.f : 0.f; tsum += mb[it];
        float a = tile[loc + 130 + it], d = tile[loc + 2 + it];
        s = fmaf(a, a, s) - d * d;
    }
    *(float4*)(out + T_LEN + 1 + bs + loc) = mf;

    // block scan
    int incl = tsum;
    for (int d = 1; d < 64; d <<= 1) { int u = __shfl_up(incl, d, 64); if (lane >= d) incl += u; }
    if (lane == 63) sh_wtot[wv] = incl;
    __syncthreads();
    int woff = 0;
    for (int q = 0; q < wv; q++) woff += sh_wtot[q];
    int texcl = woff + incl - tsum;
    int btot = sh_wtot[0] + sh_wtot[1] + sh_wtot[2] + sh_wtot[3];

    // publish aggregate, then wave-parallel lookback (wave 0), plain atomic loads
    if (tid == 0)
        __hip_atomic_store(&state[bid], (int)((1u << 30) | (unsigned)btot),
                           __ATOMIC_RELEASE, __HIP_MEMORY_SCOPE_AGENT);
    if (tid < 64) {
        int excl = 0, look = bid - 1;
        while (look >= 0) {
            int idx = look - lane;
            unsigned st = (idx >= 0)
                ? (unsigned)__hip_atomic_load(&state[idx], __ATOMIC_RELAXED,
                                              __HIP_MEMORY_SCOPE_AGENT)
                : (2u << 30);
            unsigned tag = st >> 30;
            unsigned long long pm = __ballot(tag >= 2u);
            unsigned long long im = __ballot(tag == 0u);
            int fpx = pm ? (__ffsll((long long)pm) - 1) : 64;
            unsigned long long below = (fpx >= 64) ? ~0ull : ((1ull << fpx) - 1ull);
            if (im & below) { __builtin_amdgcn_s_sleep(1); continue; }
            int contrib = (lane <= fpx) ? (int)(st & 0x3FFFFFFFu) : 0;
            for (int d = 32; d; d >>= 1) contrib += __shfl_down(contrib, d, 64);
            excl += __shfl(contrib, 0, 64);
            if (fpx < 64) break;
            look -= 64;
        }
        if (lane == 0) {
            __hip_atomic_store(&state[bid], (int)((2u << 30) | (unsigned)(excl + btot)),
                               __ATOMIC_RELEASE, __HIP_MEMORY_SCOPE_AGENT);
            sh_g0 = excl;
            if (bid == PREP_BLKS - 1) {
                *nspk = excl + btot;
                out[T_LEN] = (float)(excl + btot);
            }
        }
    }
    __syncthreads();
    int g = sh_g0 + texcl;
    #pragma unroll
    for (int it = 0; it < 4; ++it) { if (mb[it]) spk[g++] = bs + loc + it; }
}

// ---- K2: sequential GRU chain, full-row per lane (no k-split), pk-fma ----
// row i = lane&31, duplicated on upper half (wave64 issue cost identical).
// h broadcast: 1 ds_write + 8 uniform-address ds_read_b128 (HW broadcast).
__global__ __attribute__((amdgpu_waves_per_eu(2, 2)))
__launch_bounds__(64) void k_chain(const float* __restrict__ Whh,
                                   const float* __restrict__ Wih,
                                   const float* __restrict__ bih,
                                   const float* __restrict__ bhh,
                                   const int* __restrict__ spk,
                                   const float* __restrict__ x,
                                   const int* __restrict__ nspk,
                                   const float* __restrict__ Wv,
                                   const float* __restrict__ Wsc,
                                   const float* __restrict__ bv,
                                   const float* __restrict__ bs,
                                   float* __restrict__ out)
{
    __shared__ float  hh[32 * HROW + 32];      // h history + sink row
    __shared__ float2 sx[SEGL + WARMUP + 8];   // staged (t, x_t)
    __shared__ float  hb[32];                  // h broadcast
    __shared__ float  ab[2 * SEGL];            // a,b per spike

    const int lane = threadIdx.x;
    const int i = lane & 31;
    const int N = *nspk;

    // full-row weights as float4 (96 VGPRs) — v_pk_fma_f32 eligible
    v4f Wr4[8], Wz4[8], Wn4[8];
    #pragma unroll
    for (int q = 0; q < 8; q++) {
        Wr4[q] = *(const v4f*)&Whh[i * 32        + 4 * q];
        Wz4[q] = *(const v4f*)&Whh[(32 + i) * 32 + 4 * q];
        Wn4[q] = *(const v4f*)&Whh[(64 + i) * 32 + 4 * q];
    }
    const float wr0 = Wih[i * 2],        wr1 = Wih[i * 2 + 1];
    const float wz0 = Wih[(32 + i) * 2], wz1 = Wih[(32 + i) * 2 + 1];
    const float wn0 = Wih[(64 + i) * 2], wn1 = Wih[(64 + i) * 2 + 1];
    const float br  = bih[i] + bhh[i];
    const float bz  = bih[32 + i] + bhh[32 + i];
    const float bni = bih[64 + i];
    const float bnh = bhh[64 + i];

    for (int c = blockIdx.x; c * SEGL < N; c += CHAIN_BLKS) {
        const int start = c * SEGL;
        const int end = min(start + SEGL, N);
        const int s0 = max(start - WARMUP, 0);
        const int cnt = end - s0;
        const int jw = start - s0;
        const int seglen = end - start;

        for (int j = lane; j < cnt + 3; j += 64) {
            int idx = min(max(s0 - 1 + j, 0), N - 1);
            int t = spk[idx];
            sx[j] = make_float2((float)t, x[t]);
        }
        __builtin_amdgcn_wave_barrier();

        v4f hs4[8];
        #pragma unroll
        for (int q = 0; q < 8; q++) hs4[q] = (v4f)0.f;
        float hold = 0.f;

        float2 p0 = sx[0], p1 = sx[1];
        for (int j = 0; j < cnt; ++j) {
            float2 p2 = sx[j + 2];
            float d  = (p1.x - p0.x) * 0.0078125f;
            float xt = p1.y;

            v4f sr = (v4f)0.f, sz = (v4f)0.f, sn = (v4f)0.f;
            #pragma unroll
            for (int q = 0; q < 8; q++) {      // 96 FMA -> ~48 v_pk_fma_f32
                sr = Wr4[q] * hs4[q] + sr;
                sz = Wz4[q] * hs4[q] + sz;
                sn = Wn4[q] * hs4[q] + sn;
            }
            float ar = fmaf(wr1, d, fmaf(wr0, xt, br)) + ((sr.x + sr.y) + (sr.z + sr.w));
            float az = fmaf(wz1, d, fmaf(wz0, xt, bz)) + ((sz.x + sz.y) + (sz.z + sz.w));
            float an = bnh + ((sn.x + sn.y) + (sn.z + sn.w));
            float gin = fmaf(wn1, d, fmaf(wn0, xt, bni));

            float r = __builtin_amdgcn_rcpf(1.f + __builtin_amdgcn_exp2f(-1.44269504089f * ar));
            float z = __builtin_amdgcn_rcpf(1.f + __builtin_amdgcn_exp2f(-1.44269504089f * az));
            float npre = fmaf(r, an, gin);
            float en = __builtin_amdgcn_exp2f(2.88539008178f * npre);
            float n = fmaf(-2.f, __builtin_amdgcn_rcpf(1.f + en), 1.f);
            float hnew = fmaf(z, hold - n, n);
            hold = hnew;

            // h history (lanes<32, post-warmup); others -> sink row
            bool okst = (lane < 32) & (j >= jw);
            int addr = okst ? (i * HROW + (j - jw)) : (32 * HROW + i);
            hh[addr] = hnew;

            // broadcast: write h_i (dup halves, same value), read 8 x b128 uniform
            hb[i] = hnew;
            const v4f* hb4 = (const v4f*)hb;
            #pragma unroll
            for (int q = 0; q < 8; q++) hs4[q] = hb4[q];
            p0 = p1; p1 = p2;
        }
        __builtin_amdgcn_wave_barrier();

        // epilogue 1: a,b for ALL spikes of the chunk
        const float bvv = *bv, bss = *bs;
        for (int s5 = lane; s5 < seglen; s5 += 64) {
            float a = bvv, b = bss;
            #pragma unroll
            for (int k = 0; k < 32; k++) {
                float hv = hh[k * HROW + s5];
                a = fmaf(hv, Wv[k], a);
                b = fmaf(hv, Wsc[k], b);
            }
            ab[s5] = a;
            ab[SEGL + s5] = b;
        }
        __builtin_amdgcn_wave_barrier();

        // epilogue 2: expand out[t] for t in [spk[start], next chunk's first)
        const int tlo = (int)sx[jw + 1].x;
        const int thi = (end == N) ? T_LEN : (int)sx[cnt + 1].x;
        for (int t = tlo + lane; t < thi; t += 64) {
            float tf = (float)t;
            int lo = jw + 1, hi = cnt;
            #pragma unroll
            for (int itb = 0; itb < 7; ++itb) {
                int mid = (lo + hi + 1) >> 1;
                bool le = sx[mid].x <= tf;
                lo = le ? mid : lo;
                hi = le ? hi : mid - 1;
            }
            int sp = lo - (jw + 1);
            float a = ab[sp], b = ab[SEGL + sp];
            float tp = sx[lo].x;
            out[t] = fmaf(b, (tf - tp) * 0.0078125f, a);
        }
        __builtin_amdgcn_wave_barrier();
    }
}

extern "C" void kernel_launch(void* const* d_in, const int* in_sizes, int n_in,
                              void* d_out, int out_size, void* d_ws, size_t ws_size,
                              hipStream_t stream)
{
    const float* x   = (const float*)d_in[0];
    const float* Wih = (const float*)d_in[1];
    const float* Whh = (const float*)d_in[2];
    const float* bih = (const float*)d_in[3];
    const float* bhh = (const float*)d_in[4];
    const float* Wv  = (const float*)d_in[5];
    const float* bv  = (const float*)d_in[6];
    const float* Wsc = (const float*)d_in[7];
    const float* bs  = (const float*)d_in[8];
    float* out = (float*)d_out;

    char* ws = (char*)d_ws;
    int* state = (int*)(ws + OFF_STATE);
    int* nspk  = (int*)(ws + OFF_NSPK);
    int* spk   = (int*)(ws + OFF_SPK);

    hipMemsetAsync(ws, 0, 8192, stream);   // zero scan states + N
    k_prep<<<PREP_BLKS, 256, 0, stream>>>(x, out, state, nspk, spk);
    k_chain<<<CHAIN_BLKS, 64, 0, stream>>>(Whh, Wih, bih, bhh, spk, x, nspk,
                                           Wv, Wsc, bv, bs, out);
}